// Round 15
// baseline (80.956 us; speedup 1.0000x reference)
//
#include <hip/hip_runtime.h>
#include <hip/hip_bf16.h>

#define NB 8
#define LQ 4096
#define SK 4096
#define NH 8
#define DD 64
#define NPAIR (NB*NH)        // 64 (n,h) pairs
#define KVSZ (DD*DD + DD)    // 4160: 64x64 KV + 64 Ksum
#define FRAGW 768            // uint4 words of prepacked fragments per pair (12KB)

typedef short v8s __attribute__((ext_vector_type(8)));   // 8 bf16 MFMA operand
typedef float v4f __attribute__((ext_vector_type(4)));   // MFMA accumulator
union U8 { v8s s; unsigned int u[4]; uint4 q; };

__device__ __forceinline__ float fmap(float x) {
    return x > 0.f ? x + 1.f : __expf(x);   // elu+1
}
__device__ __forceinline__ unsigned short bf_hi(float x) {  // RNE fp32->bf16
    unsigned int u = __float_as_uint(x);
    return (unsigned short)((u + 0x7FFFu + ((u >> 16) & 1u)) >> 16);
}
__device__ __forceinline__ float bf_f(unsigned short b) {
    return __uint_as_float(((unsigned int)b) << 16);
}
// hi/lo bf16 split of (x0,x1) via v_cvt_pk_bf16_f32 (RNE, bit-identical to bf_hi)
__device__ __forceinline__ uint2 packsplit2(float x0, float x1) {
    union { __hip_bfloat162 b; unsigned int u; } h, l;
    h.b = __float22bfloat162_rn(make_float2(x0, x1));
    float r0 = x0 - __uint_as_float(h.u << 16);
    float r1 = x1 - __uint_as_float(h.u & 0xFFFF0000u);
    l.b = __float22bfloat162_rn(make_float2(r0, r1));
    uint2 r; r.x = h.u; r.y = l.u;
    return r;
}
#define MFMA(A, B, C) __builtin_amdgcn_mfma_f32_16x16x32_bf16((A), (B), (C), 0, 0, 0)

// ---------------- Phase 1: partial KV = K^T V via MFMA, barrier-free streaming ----
// (r12/r14 kernel, unchanged — quadrant-private waves, zero LDS/barriers)
__global__ __launch_bounds__(256, 3) void kv_partial_kernel(
    const float* __restrict__ K, const float* __restrict__ V,
    const float* __restrict__ kvm, float* __restrict__ partial, int CH)
{
    int bx = blockIdx.x;
    int chunk = bx % CH;
    int pair  = bx / CH;
    int nb = pair >> 3, h = pair & 7;
    int tid = threadIdx.x, w = tid >> 6, lane = tid & 63;
    int g = lane >> 4, c16 = lane & 15;
    int dh = w >> 1, vh = w & 1;

    v4f acc[2][2];
    v4f z4 = {0.f, 0.f, 0.f, 0.f};
    acc[0][0] = z4; acc[0][1] = z4; acc[1][0] = z4; acc[1][1] = z4;
    float ksum[2] = {0.f, 0.f};

    int SC = SK / CH;
    int tiles = SC >> 5;                 // 32-row tiles
    int rowbase = nb * SK + chunk * SC;

    const float* Kp = K + (size_t)rowbase * (NH * DD) + h * DD + 32 * dh + c16;
    const float* Vp = V + (size_t)rowbase * (NH * DD) + h * DD + 32 * vh + c16;
    const float* Mp = kvm + rowbase + 8 * g;

    auto LOADT = [&](float (&kb)[16], float (&vb)[16], float (&mb)[8], int t) {
        int s0 = (t << 5) + 8 * g;
#pragma unroll
        for (int j = 0; j < 8; ++j) {
            size_t off = (size_t)(s0 + j) * (NH * DD);
            mb[j]     = Mp[(t << 5) + j];
            kb[j]     = Kp[off];          // d = 32dh + c16       (m=0)
            kb[8 + j] = Kp[off + 16];     // d = 32dh + 16 + c16  (m=1)
            vb[j]     = Vp[off];          // v = 32vh + c16       (n=0)
            vb[8 + j] = Vp[off + 16];     // v = 32vh + 16 + c16  (n=1)
        }
    };

    auto STEP = [&](const float (&kb)[16], const float (&vb)[16], const float (&mb)[8]) {
        U8 ah[2], al[2], bh[2], bl[2];
#pragma unroll
        for (int m = 0; m < 2; ++m) {
            float xa[8];
#pragma unroll
            for (int j = 0; j < 8; ++j) xa[j] = fmap(kb[m * 8 + j]) * mb[j];
            if (vh == 0) {                // wave-uniform; avoids double-count
#pragma unroll
                for (int j = 0; j < 8; ++j) ksum[m] += xa[j];
            }
#pragma unroll
            for (int p = 0; p < 4; ++p) {
                uint2 pw = packsplit2(xa[2 * p], xa[2 * p + 1]);
                ah[m].u[p] = pw.x; al[m].u[p] = pw.y;
            }
        }
#pragma unroll
        for (int n = 0; n < 2; ++n) {
            float xb[8];
#pragma unroll
            for (int j = 0; j < 8; ++j) xb[j] = vb[n * 8 + j] * mb[j];
#pragma unroll
            for (int p = 0; p < 4; ++p) {
                uint2 pw = packsplit2(xb[2 * p], xb[2 * p + 1]);
                bh[n].u[p] = pw.x; bl[n].u[p] = pw.y;
            }
        }
#pragma unroll
        for (int m = 0; m < 2; ++m)
#pragma unroll
            for (int n = 0; n < 2; ++n) {
                acc[m][n] = MFMA(ah[m].s, bh[n].s, acc[m][n]);
                acc[m][n] = MFMA(al[m].s, bh[n].s, acc[m][n]);
                acc[m][n] = MFMA(ah[m].s, bl[n].s, acc[m][n]);
            }
    };

    float kbA[16], vbA[16], mbA[8];
    float kbB[16], vbB[16], mbB[8];

    LOADT(kbA, vbA, mbA, 0);
    if (tiles > 1) LOADT(kbB, vbB, mbB, 1);
    for (int t = 0; t < tiles; t += 2) {
        STEP(kbA, vbA, mbA);
        if (t + 2 < tiles) LOADT(kbA, vbA, mbA, t + 2);
        if (t + 1 < tiles) {
            STEP(kbB, vbB, mbB);
            if (t + 3 < tiles) LOADT(kbB, vbB, mbB, t + 3);
        }
    }

    // ---- epilogue: quadrant-private -> direct stores, no cross-wave sync ----
#pragma unroll
    for (int m = 0; m < 2; ++m) {
        ksum[m] += __shfl_xor(ksum[m], 16);
        ksum[m] += __shfl_xor(ksum[m], 32);
    }
    float* dst = partial + ((size_t)chunk * NPAIR + pair) * KVSZ;
    if (vh == 0 && lane < 16) {
        dst[4096 + 32 * dh + c16]      = ksum[0];
        dst[4096 + 32 * dh + 16 + c16] = ksum[1];
    }
#pragma unroll
    for (int m = 0; m < 2; ++m)
#pragma unroll
        for (int n = 0; n < 2; ++n)
#pragma unroll
            for (int jj = 0; jj < 4; ++jj)
                dst[(32 * dh + 16 * m + 4 * g + jj) * 64 + 32 * vh + 16 * n + c16]
                    = acc[m][n][jj];
}

// ------- Phase 1b+1c fused: reduce partials + prepack B fragments ---------
// One block per pair: sum CH partial slabs into LDS (coalesced float4), then
// emit the exact frag layout attn_out consumes. kvf buffer & one launch gone.
__global__ __launch_bounds__(256) void kv_finish_kernel(
    const float* __restrict__ partial, uint4* __restrict__ frag, int CH)
{
    int pair = blockIdx.x;
    int t = threadIdx.x;
    __shared__ float kvr[KVSZ];

    const float* src = partial + (size_t)pair * KVSZ;
    for (int e = t; e < KVSZ / 4; e += 256) {
        float4 s = make_float4(0.f, 0.f, 0.f, 0.f);
        for (int c = 0; c < CH; ++c) {
            float4 x = *(const float4*)(src + (size_t)c * NPAIR * KVSZ + 4 * e);
            s.x += x.x; s.y += x.y; s.z += x.z; s.w += x.w;
        }
        *(float4*)&kvr[4 * e] = s;
    }
    __syncthreads();

    for (int e = t; e < FRAGW; e += 256) {
        int i4 = e >> 6, lane = e & 63;
        int g = lane >> 4, c16 = lane & 15;
        unsigned int wd[4];
        if (i4 < 8) {
            int ks = i4 >> 2, nn = i4 & 3;
#pragma unroll
            for (int p = 0; p < 4; ++p) {
                float x0 = kvr[(32 * ks + 8 * g + 2 * p) * 64 + 16 * nn + c16];
                float x1 = kvr[(32 * ks + 8 * g + 2 * p + 1) * 64 + 16 * nn + c16];
                wd[p] = (unsigned int)bf_hi(x0) | ((unsigned int)bf_hi(x1) << 16);
            }
        } else {
            int j = i4 - 8, ks = j & 1, lo = j >> 1;
#pragma unroll
            for (int p = 0; p < 4; ++p) {
                unsigned int wp = 0;
                if (c16 == 0) {
                    float x0 = kvr[4096 + 32 * ks + 8 * g + 2 * p];
                    float x1 = kvr[4096 + 32 * ks + 8 * g + 2 * p + 1];
                    unsigned short h0 = bf_hi(x0), h1 = bf_hi(x1);
                    if (lo)
                        wp = (unsigned int)bf_hi(x0 - bf_f(h0)) |
                             ((unsigned int)bf_hi(x1 - bf_f(h1)) << 16);
                    else
                        wp = (unsigned int)h0 | ((unsigned int)h1 << 16);
                }
                wd[p] = wp;
            }
        }
        uint4 o; o.x = wd[0]; o.y = wd[1]; o.z = wd[2]; o.w = wd[3];
        frag[(size_t)pair * FRAGW + e] = o;
    }
}

// ---------------- Phase 2: out = (q.KV)/(q.Ksum + eps) via MFMA, no LDS --------
// NT output stores keep write-only `out` out of L3 (r14-proven, −14 µs).
__global__ __launch_bounds__(256) void attn_out_kernel(
    const float* __restrict__ Q, const float* __restrict__ qm,
    const uint4* __restrict__ frag, float* __restrict__ out)
{
    int bx = blockIdx.x;
    int pair = bx >> 5;            // 32 consecutive blocks share a pair (L2)
    int rb   = bx & 31;            // 128-row group
    int nb = pair >> 3, h = pair & 7;
    int lane = threadIdx.x & 63;
    int w    = threadIdx.x >> 6;
    int g    = lane >> 4;
    int c16  = lane & 15;

    const uint4* fb = frag + (size_t)pair * FRAGW;
    U8 Bh[2][4], Bkh[2], Bkl[2];
#pragma unroll
    for (int ks = 0; ks < 2; ++ks)
#pragma unroll
        for (int nn = 0; nn < 4; ++nn)
            Bh[ks][nn].q = fb[(ks * 4 + nn) * 64 + lane];
    Bkh[0].q = fb[8 * 64 + lane];
    Bkh[1].q = fb[9 * 64 + lane];
    Bkl[0].q = fb[10 * 64 + lane];
    Bkl[1].q = fb[11 * 64 + lane];

    float4 qA[2][4];
    float qmA[2];

    auto QLOAD = [&](int it, float4* qr, float& qmv) {
        int row = rb * 128 + (w + 4 * it) * 16 + c16;
        qmv = qm[nb * LQ + row];
        const float* qrow = Q + ((size_t)((nb * LQ + row) * NH + h)) * DD;
        qr[0] = *(const float4*)(qrow + 8 * g);
        qr[1] = *(const float4*)(qrow + 8 * g + 4);
        qr[2] = *(const float4*)(qrow + 8 * g + 32);
        qr[3] = *(const float4*)(qrow + 8 * g + 36);
    };

    v4f z4 = {0.f, 0.f, 0.f, 0.f};
    QLOAD(0, qA[0], qmA[0]);
#pragma unroll
    for (int it = 0; it < 2; ++it) {
        if (it == 0) QLOAD(1, qA[1], qmA[1]);   // prefetch under pack+MFMA
        const float4* qr = qA[it];
        float qmv = qmA[it];

        U8 Ah[2], Al[2];
#pragma unroll
        for (int ks = 0; ks < 2; ++ks) {
            float qv[8] = {qr[2*ks].x, qr[2*ks].y, qr[2*ks].z, qr[2*ks].w,
                           qr[2*ks+1].x, qr[2*ks+1].y, qr[2*ks+1].z, qr[2*ks+1].w};
#pragma unroll
            for (int p = 0; p < 4; ++p) {
                uint2 pw = packsplit2(fmap(qv[2*p]) * qmv, fmap(qv[2*p+1]) * qmv);
                Ah[ks].u[p] = pw.x;
                Al[ks].u[p] = pw.y;
            }
        }

        v4f a0 = z4, a1 = z4, a2 = z4, a3 = z4, a4 = z4;
#pragma unroll
        for (int ks = 0; ks < 2; ++ks) {
            a0 = MFMA(Ah[ks].s, Bh[ks][0].s, a0);
            a1 = MFMA(Ah[ks].s, Bh[ks][1].s, a1);
            a2 = MFMA(Ah[ks].s, Bh[ks][2].s, a2);
            a3 = MFMA(Ah[ks].s, Bh[ks][3].s, a3);
            a0 = MFMA(Al[ks].s, Bh[ks][0].s, a0);
            a1 = MFMA(Al[ks].s, Bh[ks][1].s, a1);
            a2 = MFMA(Al[ks].s, Bh[ks][2].s, a2);
            a3 = MFMA(Al[ks].s, Bh[ks][3].s, a3);
            a4 = MFMA(Ah[ks].s, Bkh[ks].s, a4);
            a4 = MFMA(Al[ks].s, Bkh[ks].s, a4);
            a4 = MFMA(Ah[ks].s, Bkl[ks].s, a4);
        }

        int row0 = rb * 128 + (w + 4 * it) * 16;
        int src = lane & 48;
#pragma unroll
        for (int jj = 0; jj < 4; ++jj) {
            float den = __shfl(a4[jj], src);
            float z = 1.f / (den + 1e-6f);
            size_t ob = ((size_t)((nb * LQ + row0 + 4 * g + jj) * NH + h)) * DD + c16;
            __builtin_nontemporal_store(a0[jj] * z, &out[ob]);
            __builtin_nontemporal_store(a1[jj] * z, &out[ob + 16]);
            __builtin_nontemporal_store(a2[jj] * z, &out[ob + 32]);
            __builtin_nontemporal_store(a3[jj] * z, &out[ob + 48]);
        }
    }
}

extern "C" void kernel_launch(void* const* d_in, const int* in_sizes, int n_in,
                              void* d_out, int out_size, void* d_ws, size_t ws_size,
                              hipStream_t stream) {
    const float* Q   = (const float*)d_in[0];
    const float* K   = (const float*)d_in[1];
    const float* V   = (const float*)d_in[2];
    const float* qm  = (const float*)d_in[3];
    const float* kvm = (const float*)d_in[4];
    float* out = (float*)d_out;

    int CH = 16;   // 1024 blocks
    while (CH > 1 && (size_t)CH * NPAIR * KVSZ * sizeof(float)
                         + (size_t)NPAIR * FRAGW * 16 > ws_size) CH >>= 1;

    float* partial = (float*)d_ws;
    uint4* frag = (uint4*)((char*)d_ws + (size_t)CH * NPAIR * KVSZ * sizeof(float));

    kv_partial_kernel<<<dim3(NPAIR * CH), dim3(256), 0, stream>>>(K, V, kvm, partial, CH);
    kv_finish_kernel<<<dim3(NPAIR), dim3(256), 0, stream>>>(partial, frag, CH);
    attn_out_kernel<<<dim3(NPAIR * 32), dim3(256), 0, stream>>>(Q, qm, frag, out);
}

// Round 16
// 66.445 us; speedup vs baseline: 1.2184x; 1.2184x over previous
//
#include <hip/hip_runtime.h>
#include <hip/hip_bf16.h>

#define NB 8
#define LQ 4096
#define SK 4096
#define NH 8
#define DD 64
#define NPAIR (NB*NH)        // 64 (n,h) pairs
#define KVSZ (DD*DD + DD)    // 4160: 64x64 KV + 64 Ksum
#define FRAGW 768            // uint4 words of prepacked fragments per pair (12KB)

typedef short v8s __attribute__((ext_vector_type(8)));   // 8 bf16 MFMA operand
typedef float v4f __attribute__((ext_vector_type(4)));   // MFMA accumulator
union U8 { v8s s; unsigned int u[4]; uint4 q; };

__device__ __forceinline__ float fmap(float x) {
    return x > 0.f ? x + 1.f : __expf(x);   // elu+1
}
__device__ __forceinline__ unsigned short bf_hi(float x) {  // RNE fp32->bf16
    unsigned int u = __float_as_uint(x);
    return (unsigned short)((u + 0x7FFFu + ((u >> 16) & 1u)) >> 16);
}
__device__ __forceinline__ float bf_f(unsigned short b) {
    return __uint_as_float(((unsigned int)b) << 16);
}
// hi/lo bf16 split of (x0,x1) via v_cvt_pk_bf16_f32 (RNE, bit-identical to bf_hi)
__device__ __forceinline__ uint2 packsplit2(float x0, float x1) {
    union { __hip_bfloat162 b; unsigned int u; } h, l;
    h.b = __float22bfloat162_rn(make_float2(x0, x1));
    float r0 = x0 - __uint_as_float(h.u << 16);
    float r1 = x1 - __uint_as_float(h.u & 0xFFFF0000u);
    l.b = __float22bfloat162_rn(make_float2(r0, r1));
    uint2 r; r.x = h.u; r.y = l.u;
    return r;
}
#define MFMA(A, B, C) __builtin_amdgcn_mfma_f32_16x16x32_bf16((A), (B), (C), 0, 0, 0)

// ---------------- Phase 1: partial KV = K^T V via MFMA, barrier-free streaming ----
// (r12/r14 kernel, unchanged — quadrant-private waves, zero LDS/barriers)
__global__ __launch_bounds__(256, 3) void kv_partial_kernel(
    const float* __restrict__ K, const float* __restrict__ V,
    const float* __restrict__ kvm, float* __restrict__ partial, int CH)
{
    int bx = blockIdx.x;
    int chunk = bx % CH;
    int pair  = bx / CH;
    int nb = pair >> 3, h = pair & 7;
    int tid = threadIdx.x, w = tid >> 6, lane = tid & 63;
    int g = lane >> 4, c16 = lane & 15;
    int dh = w >> 1, vh = w & 1;

    v4f acc[2][2];
    v4f z4 = {0.f, 0.f, 0.f, 0.f};
    acc[0][0] = z4; acc[0][1] = z4; acc[1][0] = z4; acc[1][1] = z4;
    float ksum[2] = {0.f, 0.f};

    int SC = SK / CH;
    int tiles = SC >> 5;                 // 32-row tiles
    int rowbase = nb * SK + chunk * SC;

    const float* Kp = K + (size_t)rowbase * (NH * DD) + h * DD + 32 * dh + c16;
    const float* Vp = V + (size_t)rowbase * (NH * DD) + h * DD + 32 * vh + c16;
    const float* Mp = kvm + rowbase + 8 * g;

    auto LOADT = [&](float (&kb)[16], float (&vb)[16], float (&mb)[8], int t) {
        int s0 = (t << 5) + 8 * g;
#pragma unroll
        for (int j = 0; j < 8; ++j) {
            size_t off = (size_t)(s0 + j) * (NH * DD);
            mb[j]     = Mp[(t << 5) + j];
            kb[j]     = Kp[off];          // d = 32dh + c16       (m=0)
            kb[8 + j] = Kp[off + 16];     // d = 32dh + 16 + c16  (m=1)
            vb[j]     = Vp[off];          // v = 32vh + c16       (n=0)
            vb[8 + j] = Vp[off + 16];     // v = 32vh + 16 + c16  (n=1)
        }
    };

    auto STEP = [&](const float (&kb)[16], const float (&vb)[16], const float (&mb)[8]) {
        U8 ah[2], al[2], bh[2], bl[2];
#pragma unroll
        for (int m = 0; m < 2; ++m) {
            float xa[8];
#pragma unroll
            for (int j = 0; j < 8; ++j) xa[j] = fmap(kb[m * 8 + j]) * mb[j];
            if (vh == 0) {                // wave-uniform; avoids double-count
#pragma unroll
                for (int j = 0; j < 8; ++j) ksum[m] += xa[j];
            }
#pragma unroll
            for (int p = 0; p < 4; ++p) {
                uint2 pw = packsplit2(xa[2 * p], xa[2 * p + 1]);
                ah[m].u[p] = pw.x; al[m].u[p] = pw.y;
            }
        }
#pragma unroll
        for (int n = 0; n < 2; ++n) {
            float xb[8];
#pragma unroll
            for (int j = 0; j < 8; ++j) xb[j] = vb[n * 8 + j] * mb[j];
#pragma unroll
            for (int p = 0; p < 4; ++p) {
                uint2 pw = packsplit2(xb[2 * p], xb[2 * p + 1]);
                bh[n].u[p] = pw.x; bl[n].u[p] = pw.y;
            }
        }
#pragma unroll
        for (int m = 0; m < 2; ++m)
#pragma unroll
            for (int n = 0; n < 2; ++n) {
                acc[m][n] = MFMA(ah[m].s, bh[n].s, acc[m][n]);
                acc[m][n] = MFMA(al[m].s, bh[n].s, acc[m][n]);
                acc[m][n] = MFMA(ah[m].s, bl[n].s, acc[m][n]);
            }
    };

    float kbA[16], vbA[16], mbA[8];
    float kbB[16], vbB[16], mbB[8];

    LOADT(kbA, vbA, mbA, 0);
    if (tiles > 1) LOADT(kbB, vbB, mbB, 1);
    for (int t = 0; t < tiles; t += 2) {
        STEP(kbA, vbA, mbA);
        if (t + 2 < tiles) LOADT(kbA, vbA, mbA, t + 2);
        if (t + 1 < tiles) {
            STEP(kbB, vbB, mbB);
            if (t + 3 < tiles) LOADT(kbB, vbB, mbB, t + 3);
        }
    }

    // ---- epilogue: quadrant-private -> direct stores, no cross-wave sync ----
#pragma unroll
    for (int m = 0; m < 2; ++m) {
        ksum[m] += __shfl_xor(ksum[m], 16);
        ksum[m] += __shfl_xor(ksum[m], 32);
    }
    float* dst = partial + ((size_t)chunk * NPAIR + pair) * KVSZ;
    if (vh == 0 && lane < 16) {
        dst[4096 + 32 * dh + c16]      = ksum[0];
        dst[4096 + 32 * dh + 16 + c16] = ksum[1];
    }
#pragma unroll
    for (int m = 0; m < 2; ++m)
#pragma unroll
        for (int n = 0; n < 2; ++n)
#pragma unroll
            for (int jj = 0; jj < 4; ++jj)
                dst[(32 * dh + 16 * m + 4 * g + jj) * 64 + 32 * vh + 16 * n + c16]
                    = acc[m][n][jj];
}

// ---------------- Phase 1b: reduce partials over chunks (1040 blocks) -----------
// NT loads: partial is read-once-then-dead — keep it from displacing K/V/Q in L3.
__global__ __launch_bounds__(256) void kv_reduce_kernel(
    const float* __restrict__ partial, float* __restrict__ kvf, int CH)
{
    int i = blockIdx.x * 256 + threadIdx.x;
    if (i >= NPAIR * KVSZ) return;
    float s = 0.f;
    for (int c = 0; c < CH; ++c)
        s += __builtin_nontemporal_load(partial + (size_t)c * NPAIR * KVSZ + i);
    kvf[i] = s;
}

// ---------------- Phase 1c: prepack B fragments (bf16) for attn_out --------
__global__ __launch_bounds__(256) void kv_pack_kernel(
    const float* __restrict__ kvf, uint4* __restrict__ frag)
{
    int pair = blockIdx.x;
    int t = threadIdx.x;
    __shared__ float kvr[KVSZ];
    const float* src = kvf + (size_t)pair * KVSZ;
    for (int e = t; e < KVSZ / 4; e += 256)
        *(float4*)&kvr[4 * e] = *(const float4*)(src + 4 * e);
    __syncthreads();

    for (int e = t; e < FRAGW; e += 256) {
        int i4 = e >> 6, lane = e & 63;
        int g = lane >> 4, c16 = lane & 15;
        unsigned int wd[4];
        if (i4 < 8) {
            int ks = i4 >> 2, nn = i4 & 3;
#pragma unroll
            for (int p = 0; p < 4; ++p) {
                float x0 = kvr[(32 * ks + 8 * g + 2 * p) * 64 + 16 * nn + c16];
                float x1 = kvr[(32 * ks + 8 * g + 2 * p + 1) * 64 + 16 * nn + c16];
                wd[p] = (unsigned int)bf_hi(x0) | ((unsigned int)bf_hi(x1) << 16);
            }
        } else {
            int j = i4 - 8, ks = j & 1, lo = j >> 1;
#pragma unroll
            for (int p = 0; p < 4; ++p) {
                unsigned int wp = 0;
                if (c16 == 0) {
                    float x0 = kvr[4096 + 32 * ks + 8 * g + 2 * p];
                    float x1 = kvr[4096 + 32 * ks + 8 * g + 2 * p + 1];
                    unsigned short h0 = bf_hi(x0), h1 = bf_hi(x1);
                    if (lo)
                        wp = (unsigned int)bf_hi(x0 - bf_f(h0)) |
                             ((unsigned int)bf_hi(x1 - bf_f(h1)) << 16);
                    else
                        wp = (unsigned int)h0 | ((unsigned int)h1 << 16);
                }
                wd[p] = wp;
            }
        }
        uint4 o; o.x = wd[0]; o.y = wd[1]; o.z = wd[2]; o.w = wd[3];
        frag[(size_t)pair * FRAGW + e] = o;
    }
}

// ---------------- Phase 2: out = (q.KV)/(q.Ksum + eps) via MFMA, no LDS --------
// NT output stores keep write-only `out` out of L3 (r14-proven).
__global__ __launch_bounds__(256) void attn_out_kernel(
    const float* __restrict__ Q, const float* __restrict__ qm,
    const uint4* __restrict__ frag, float* __restrict__ out)
{
    int bx = blockIdx.x;
    int pair = bx >> 5;            // 32 consecutive blocks share a pair (L2)
    int rb   = bx & 31;            // 128-row group
    int nb = pair >> 3, h = pair & 7;
    int lane = threadIdx.x & 63;
    int w    = threadIdx.x >> 6;
    int g    = lane >> 4;
    int c16  = lane & 15;

    const uint4* fb = frag + (size_t)pair * FRAGW;
    U8 Bh[2][4], Bkh[2], Bkl[2];
#pragma unroll
    for (int ks = 0; ks < 2; ++ks)
#pragma unroll
        for (int nn = 0; nn < 4; ++nn)
            Bh[ks][nn].q = fb[(ks * 4 + nn) * 64 + lane];
    Bkh[0].q = fb[8 * 64 + lane];
    Bkh[1].q = fb[9 * 64 + lane];
    Bkl[0].q = fb[10 * 64 + lane];
    Bkl[1].q = fb[11 * 64 + lane];

    float4 qA[2][4];
    float qmA[2];

    auto QLOAD = [&](int it, float4* qr, float& qmv) {
        int row = rb * 128 + (w + 4 * it) * 16 + c16;
        qmv = qm[nb * LQ + row];
        const float* qrow = Q + ((size_t)((nb * LQ + row) * NH + h)) * DD;
        qr[0] = *(const float4*)(qrow + 8 * g);
        qr[1] = *(const float4*)(qrow + 8 * g + 4);
        qr[2] = *(const float4*)(qrow + 8 * g + 32);
        qr[3] = *(const float4*)(qrow + 8 * g + 36);
    };

    v4f z4 = {0.f, 0.f, 0.f, 0.f};
    QLOAD(0, qA[0], qmA[0]);
#pragma unroll
    for (int it = 0; it < 2; ++it) {
        if (it == 0) QLOAD(1, qA[1], qmA[1]);   // prefetch under pack+MFMA
        const float4* qr = qA[it];
        float qmv = qmA[it];

        U8 Ah[2], Al[2];
#pragma unroll
        for (int ks = 0; ks < 2; ++ks) {
            float qv[8] = {qr[2*ks].x, qr[2*ks].y, qr[2*ks].z, qr[2*ks].w,
                           qr[2*ks+1].x, qr[2*ks+1].y, qr[2*ks+1].z, qr[2*ks+1].w};
#pragma unroll
            for (int p = 0; p < 4; ++p) {
                uint2 pw = packsplit2(fmap(qv[2*p]) * qmv, fmap(qv[2*p+1]) * qmv);
                Ah[ks].u[p] = pw.x;
                Al[ks].u[p] = pw.y;
            }
        }

        v4f a0 = z4, a1 = z4, a2 = z4, a3 = z4, a4 = z4;
#pragma unroll
        for (int ks = 0; ks < 2; ++ks) {
            a0 = MFMA(Ah[ks].s, Bh[ks][0].s, a0);
            a1 = MFMA(Ah[ks].s, Bh[ks][1].s, a1);
            a2 = MFMA(Ah[ks].s, Bh[ks][2].s, a2);
            a3 = MFMA(Ah[ks].s, Bh[ks][3].s, a3);
            a0 = MFMA(Al[ks].s, Bh[ks][0].s, a0);
            a1 = MFMA(Al[ks].s, Bh[ks][1].s, a1);
            a2 = MFMA(Al[ks].s, Bh[ks][2].s, a2);
            a3 = MFMA(Al[ks].s, Bh[ks][3].s, a3);
            a4 = MFMA(Ah[ks].s, Bkh[ks].s, a4);
            a4 = MFMA(Al[ks].s, Bkh[ks].s, a4);
            a4 = MFMA(Ah[ks].s, Bkl[ks].s, a4);
        }

        int row0 = rb * 128 + (w + 4 * it) * 16;
        int src = lane & 48;
#pragma unroll
        for (int jj = 0; jj < 4; ++jj) {
            float den = __shfl(a4[jj], src);
            float z = 1.f / (den + 1e-6f);
            size_t ob = ((size_t)((nb * LQ + row0 + 4 * g + jj) * NH + h)) * DD + c16;
            __builtin_nontemporal_store(a0[jj] * z, &out[ob]);
            __builtin_nontemporal_store(a1[jj] * z, &out[ob + 16]);
            __builtin_nontemporal_store(a2[jj] * z, &out[ob + 32]);
            __builtin_nontemporal_store(a3[jj] * z, &out[ob + 48]);
        }
    }
}

extern "C" void kernel_launch(void* const* d_in, const int* in_sizes, int n_in,
                              void* d_out, int out_size, void* d_ws, size_t ws_size,
                              hipStream_t stream) {
    const float* Q   = (const float*)d_in[0];
    const float* K   = (const float*)d_in[1];
    const float* V   = (const float*)d_in[2];
    const float* qm  = (const float*)d_in[3];
    const float* kvm = (const float*)d_in[4];
    float* out = (float*)d_out;

    int CH = 16;   // 1024 blocks
    while (CH > 1 && (size_t)(CH + 1) * NPAIR * KVSZ * sizeof(float) > ws_size) CH >>= 1;

    float* partial = (float*)d_ws;
    float* kvf = partial + (size_t)CH * NPAIR * KVSZ;
    // frag overlays partial slab 0 (partial is dead once kv_reduce has run)
    uint4* frag = (uint4*)d_ws;

    kv_partial_kernel<<<dim3(NPAIR * CH), dim3(256), 0, stream>>>(K, V, kvm, partial, CH);
    kv_reduce_kernel<<<dim3((NPAIR * KVSZ + 255) / 256), dim3(256), 0, stream>>>(partial, kvf, CH);
    kv_pack_kernel<<<dim3(NPAIR), dim3(256), 0, stream>>>(kvf, frag);
    attn_out_kernel<<<dim3(NPAIR * 32), dim3(256), 0, stream>>>(Q, qm, frag, out);
}